// Round 6
// baseline (109.787 us; speedup 1.0000x reference)
//
#include <hip/hip_runtime.h>

// Pool255: out = (1/8) * sum of 8 directional cumulative-max pools.
// x: [8,256,128,128] fp32. One block (2 waves) per image, ZERO LDS.
//
// Wave0 sweeps rows top-down computing dirs {(-1,0),(-1,-1),(-1,+1),(0,-1)};
// wave1 sweeps bottom-up in a COLUMN-MIRRORED view (lane l <-> col 127-2l),
// which turns its 4 dirs {(1,0),(1,1),(1,-1),(0,1)} into the SAME recurrences.
// Lane l owns 2 adjacent (view-)columns {2l,2l+1}: vertical = register max,
// diag/anti = 1 ds_bpermute each, row prefix-max = 6-step DPP scan + 1
// bpermute.
//
// R6: partial handoff goes through the OUT buffer instead of LDS (fp16x2
// packed into the low 4 bytes of each lane's 8-byte final slot). Phase 0
// writes partial; __syncthreads() (vmcnt-drain + barrier -> stores visible
// block-wide through the per-CU L1/L2); phase 1 reads the other wave's
// partial word and overwrites the full float2 with the final value. Each
// slot is read-then-overwritten by the same lane: no hazards, deterministic.
// Zero LDS -> all 8 blocks/CU co-resident (16 waves/CU vs ~3 blocks before).
// Depth-4 prefetch pipelines for both x and the partial words.

#define NPIX 16384
#define NEGF (-3.402823466e38f)

typedef __fp16 half2v __attribute__((ext_vector_type(2)));

// y = max(y, dpp_move(y)) ; masked lanes keep old=y (no-op)
#define DPP_MAXSTEP(y, ctrl, rmask)                                          \
  y = fmaxf(y, __int_as_float(__builtin_amdgcn_update_dpp(                   \
                 __float_as_int(y), __float_as_int(y), ctrl, rmask, 0xf,     \
                 false)))

template <bool MIR>
__device__ __forceinline__ void run(const float* __restrict__ xim,
                                    float* __restrict__ oim, const int l,
                                    const int addr_m1, const int addr_p1) {
  const int off = MIR ? (63 - l) * 2 : l * 2;  // float index of the col pair
  unsigned* __restrict__ pw = (unsigned*)oim;  // partial word view (u32)

  float v0 = NEGF, v1 = NEGF, d0 = NEGF, d1 = NEGF, a0 = NEGF, a1 = NEGF;

  // depth-4 x-load pipeline
  float2 G[4];
#pragma unroll
  for (int k = 0; k < 4; ++k) {
    const int row = MIR ? 127 - k : k;
    G[k] = *(const float2*)(xim + (row << 7) + off);
  }

  // ---- phase 0: t = 0..63, write fp16x2 partial into out's low word ----
  for (int tb = 0; tb < 64; tb += 4) {
#pragma unroll
    for (int k = 0; k < 4; ++k) {
      const int t = tb + k;
      const float2 xv = G[k];
      const int pr = t + 4;  // 4..67: tail pre-issues phase-1 x rows
      const int prow = MIR ? 127 - pr : pr;
      G[k] = *(const float2*)(xim + (prow << 7) + off);

      const float x0 = MIR ? xv.y : xv.x;
      const float x1 = MIR ? xv.x : xv.y;

      v0 = fmaxf(v0, x0);
      v1 = fmaxf(v1, x1);

      float pd = __int_as_float(
          __builtin_amdgcn_ds_bpermute(addr_m1, __float_as_int(d1)));
      pd = (l == 0) ? NEGF : pd;
      const float nd0 = fmaxf(x0, pd);
      const float nd1 = fmaxf(x1, d0);
      d0 = nd0; d1 = nd1;

      float pa = __int_as_float(
          __builtin_amdgcn_ds_bpermute(addr_p1, __float_as_int(a0)));
      pa = (l == 63) ? NEGF : pa;
      const float na1 = fmaxf(x1, pa);
      const float na0 = fmaxf(x0, a1);
      a0 = na0; a1 = na1;

      float y = fmaxf(x0, x1);
      DPP_MAXSTEP(y, 0x111, 0xf);  // row_shr:1
      DPP_MAXSTEP(y, 0x112, 0xf);  // row_shr:2
      DPP_MAXSTEP(y, 0x114, 0xf);  // row_shr:4
      DPP_MAXSTEP(y, 0x118, 0xf);  // row_shr:8
      DPP_MAXSTEP(y, 0x142, 0xa);  // row_bcast15 -> rows 1,3
      DPP_MAXSTEP(y, 0x143, 0xc);  // row_bcast31 -> rows 2,3
      float ex = __int_as_float(
          __builtin_amdgcn_ds_bpermute(addr_m1, __float_as_int(y)));
      ex = (l == 0) ? NEGF : ex;
      const float s0 = fmaxf(ex, x0);

      const float p0 = (v0 + d0) + (a0 + s0);
      const float p1 = (v1 + d1) + (a1 + y);

      const int row = MIR ? 127 - t : t;
      const half2v h = MIR ? __builtin_amdgcn_cvt_pkrtz(p1, p0)
                           : __builtin_amdgcn_cvt_pkrtz(p0, p1);
      pw[(row << 7) + off] = __builtin_bit_cast(unsigned, h);
    }
  }

  __syncthreads();  // vmcnt(0) drain + barrier: partials visible block-wide

  // ---- phase 1: t = 64..127, combine + store final float2 ----
  {
    // depth-4 partial-word pipeline (must start AFTER the barrier)
    unsigned Q[4];
#pragma unroll
    for (int k = 0; k < 4; ++k) {
      const int row = MIR ? 127 - (64 + k) : (64 + k);
      Q[k] = pw[(row << 7) + off];
    }
    for (int tb = 64; tb < 128; tb += 4) {
#pragma unroll
      for (int k = 0; k < 4; ++k) {
        const int t = tb + k;
        const float2 xv = G[k];
        const int pr = (t + 4 < 128) ? t + 4 : 127;  // clamp (uniform)
        const int prow = MIR ? 127 - pr : pr;
        G[k] = *(const float2*)(xim + (prow << 7) + off);

        const unsigned q = Q[k];
        Q[k] = pw[(prow << 7) + off];  // prefetch partial row t+4 (clamped)

        const float x0 = MIR ? xv.y : xv.x;
        const float x1 = MIR ? xv.x : xv.y;

        v0 = fmaxf(v0, x0);
        v1 = fmaxf(v1, x1);

        float pd = __int_as_float(
            __builtin_amdgcn_ds_bpermute(addr_m1, __float_as_int(d1)));
        pd = (l == 0) ? NEGF : pd;
        const float nd0 = fmaxf(x0, pd);
        const float nd1 = fmaxf(x1, d0);
        d0 = nd0; d1 = nd1;

        float pa = __int_as_float(
            __builtin_amdgcn_ds_bpermute(addr_p1, __float_as_int(a0)));
        pa = (l == 63) ? NEGF : pa;
        const float na1 = fmaxf(x1, pa);
        const float na0 = fmaxf(x0, a1);
        a0 = na0; a1 = na1;

        float y = fmaxf(x0, x1);
        DPP_MAXSTEP(y, 0x111, 0xf);
        DPP_MAXSTEP(y, 0x112, 0xf);
        DPP_MAXSTEP(y, 0x114, 0xf);
        DPP_MAXSTEP(y, 0x118, 0xf);
        DPP_MAXSTEP(y, 0x142, 0xa);
        DPP_MAXSTEP(y, 0x143, 0xc);
        float ex = __int_as_float(
            __builtin_amdgcn_ds_bpermute(addr_m1, __float_as_int(y)));
        ex = (l == 0) ? NEGF : ex;
        const float s0 = fmaxf(ex, x0);

        const float p0 = (v0 + d0) + (a0 + s0);
        const float p1 = (v1 + d1) + (a1 + y);

        const half2v hq = __builtin_bit_cast(half2v, q);
        const float q0 = (float)(MIR ? hq.y : hq.x);
        const float q1 = (float)(MIR ? hq.x : hq.y);
        const float o0 = (p0 + q0) * 0.125f;
        const float o1 = (p1 + q1) * 0.125f;

        const int row = MIR ? 127 - t : t;
        const float2 ov = MIR ? make_float2(o1, o0) : make_float2(o0, o1);
        *(float2*)(oim + (row << 7) + off) = ov;
      }
    }
  }
}

__global__ __launch_bounds__(128) void pool255_sweep(
    const float* __restrict__ x, float* __restrict__ out) {
  const int img = blockIdx.x;
  const float* __restrict__ xim = x + (size_t)img * NPIX;
  float* __restrict__ oim = out + (size_t)img * NPIX;
  const int l = threadIdx.x & 63;
  const int addr_m1 = ((l - 1) & 63) * 4;  // wraps; lane0 fixed by cndmask
  const int addr_p1 = ((l + 1) & 63) * 4;  // wraps; lane63 fixed by cndmask

  if (threadIdx.x < 64)
    run<false>(xim, oim, l, addr_m1, addr_p1);
  else
    run<true>(xim, oim, l, addr_m1, addr_p1);
}

extern "C" void kernel_launch(void* const* d_in, const int* in_sizes, int n_in,
                              void* d_out, int out_size, void* d_ws,
                              size_t ws_size, hipStream_t stream) {
  const float* x = (const float*)d_in[0];
  float* out = (float*)d_out;
  const int n_img = in_sizes[0] / NPIX;  // 8*256 = 2048
  pool255_sweep<<<n_img, 128, 0, stream>>>(x, out);
}

// Round 7
// 75.513 us; speedup vs baseline: 1.4539x; 1.4539x over previous
//
#include <hip/hip_runtime.h>

// Pool255: out = (1/8) * sum of 8 directional cumulative-max pools.
// x: [8,256,128,128] fp32. One block (2 waves) per image, 32 KB LDS.
//
// Wave0 sweeps rows top-down computing dirs {(-1,0),(-1,-1),(-1,+1),(0,-1)};
// wave1 sweeps bottom-up in a COLUMN-MIRRORED view (lane l <-> col 127-2l),
// which turns its 4 dirs {(1,0),(1,1),(1,-1),(0,1)} into the SAME recurrences.
// Lane l owns 2 adjacent (view-)columns {2l,2l+1}.
//
// R7: ALL cross-lane shift-by-1 ops are DPP wave_shr:1 / wave_shl:1 (pure
// VALU, `old` operand supplies the NEGF boundary) instead of ds_bpermute.
// Zero LDS ops in the recurrence chain; LDS only for the fp16x2 partial
// handoff (1 write + 1 read per row). Depth-4 global prefetch as in R5.

#define NPIX 16384
#define NEGF (-3.402823466e38f)

typedef __fp16 half2v __attribute__((ext_vector_type(2)));

// dst[l] = src[l-CTRL dir]; invalid lanes get `oldv`.
template <int CTRL>
__device__ __forceinline__ float dpp_movf(float oldv, float src) {
  return __int_as_float(__builtin_amdgcn_update_dpp(
      __float_as_int(oldv), __float_as_int(src), CTRL, 0xf, 0xf, false));
}
#define WAVE_SHR1 0x138  // lane l reads lane l-1 (lane 0 invalid)
#define WAVE_SHL1 0x130  // lane l reads lane l+1 (lane 63 invalid)

// y = max(y, dpp_move(y)) ; masked/invalid lanes keep old=y (no-op)
#define DPP_MAXSTEP(y, ctrl, rmask)                                          \
  y = fmaxf(y, __int_as_float(__builtin_amdgcn_update_dpp(                   \
                 __float_as_int(y), __float_as_int(y), ctrl, rmask, 0xf,     \
                 false)))

template <bool MIR>
__device__ __forceinline__ void run(const float* __restrict__ xim,
                                    float* __restrict__ oim,
                                    unsigned* __restrict__ part, const int l) {
  const int off = MIR ? (63 - l) * 2 : l * 2;  // float index of the col pair
  const int slot = MIR ? (63 - l) : l;         // u32 slot in a part row

  float v0 = NEGF, v1 = NEGF, d0 = NEGF, d1 = NEGF, a0 = NEGF, a1 = NEGF;

  // depth-4 x-load pipeline
  float2 G[4];
#pragma unroll
  for (int k = 0; k < 4; ++k) {
    const int row = MIR ? 127 - k : k;
    G[k] = *(const float2*)(xim + (row << 7) + off);
  }

  // ---- phase 0: t = 0..63, write fp16x2 partial to LDS ----
  for (int tb = 0; tb < 64; tb += 4) {
#pragma unroll
    for (int k = 0; k < 4; ++k) {
      const int t = tb + k;
      const float2 xv = G[k];
      const int pr = t + 4;  // 4..67: tail pre-issues phase-1 x rows
      const int prow = MIR ? 127 - pr : pr;
      G[k] = *(const float2*)(xim + (prow << 7) + off);

      const float x0 = MIR ? xv.y : xv.x;
      const float x1 = MIR ? xv.x : xv.y;

      v0 = fmaxf(v0, x0);
      v1 = fmaxf(v1, x1);

      // diagonal: D[c] = max(x[c], Dprev[c-1])
      const float pd = dpp_movf<WAVE_SHR1>(NEGF, d1);
      const float nd0 = fmaxf(x0, pd);
      const float nd1 = fmaxf(x1, d0);
      d0 = nd0; d1 = nd1;

      // anti-diagonal: A[c] = max(x[c], Aprev[c+1])
      const float pa = dpp_movf<WAVE_SHL1>(NEGF, a0);
      const float na1 = fmaxf(x1, pa);
      const float na0 = fmaxf(x0, a1);
      a0 = na0; a1 = na1;

      // row inclusive prefix-max over lane totals (DPP scan)
      float y = fmaxf(x0, x1);
      DPP_MAXSTEP(y, 0x111, 0xf);  // row_shr:1
      DPP_MAXSTEP(y, 0x112, 0xf);  // row_shr:2
      DPP_MAXSTEP(y, 0x114, 0xf);  // row_shr:4
      DPP_MAXSTEP(y, 0x118, 0xf);  // row_shr:8
      DPP_MAXSTEP(y, 0x142, 0xa);  // row_bcast15 -> rows 1,3
      DPP_MAXSTEP(y, 0x143, 0xc);  // row_bcast31 -> rows 2,3
      const float ex = dpp_movf<WAVE_SHR1>(NEGF, y);
      const float s0 = fmaxf(ex, x0);

      const float p0 = (v0 + d0) + (a0 + s0);
      const float p1 = (v1 + d1) + (a1 + y);

      const int row = MIR ? 127 - t : t;
      const half2v h = MIR ? __builtin_amdgcn_cvt_pkrtz(p1, p0)
                           : __builtin_amdgcn_cvt_pkrtz(p0, p1);
      part[(row << 6) + slot] = __builtin_bit_cast(unsigned, h);
    }
  }

  __syncthreads();

  // ---- phase 1: t = 64..127, combine + store final float2 ----
  {
    const int row64 = MIR ? 63 : 64;
    unsigned pb = part[(row64 << 6) + slot];
    for (int tb = 64; tb < 128; tb += 4) {
#pragma unroll
      for (int k = 0; k < 4; ++k) {
        const int t = tb + k;
        const float2 xv = G[k];
        const int pr = (t + 4 < 128) ? t + 4 : 127;  // clamp (uniform)
        const int prow = MIR ? 127 - pr : pr;
        G[k] = *(const float2*)(xim + (prow << 7) + off);

        const unsigned q = pb;
        const int tn = (t + 1 < 128) ? t + 1 : 127;
        const int nrow = MIR ? 127 - tn : tn;
        pb = part[(nrow << 6) + slot];  // 1-deep LDS prefetch

        const float x0 = MIR ? xv.y : xv.x;
        const float x1 = MIR ? xv.x : xv.y;

        v0 = fmaxf(v0, x0);
        v1 = fmaxf(v1, x1);

        const float pd = dpp_movf<WAVE_SHR1>(NEGF, d1);
        const float nd0 = fmaxf(x0, pd);
        const float nd1 = fmaxf(x1, d0);
        d0 = nd0; d1 = nd1;

        const float pa = dpp_movf<WAVE_SHL1>(NEGF, a0);
        const float na1 = fmaxf(x1, pa);
        const float na0 = fmaxf(x0, a1);
        a0 = na0; a1 = na1;

        float y = fmaxf(x0, x1);
        DPP_MAXSTEP(y, 0x111, 0xf);
        DPP_MAXSTEP(y, 0x112, 0xf);
        DPP_MAXSTEP(y, 0x114, 0xf);
        DPP_MAXSTEP(y, 0x118, 0xf);
        DPP_MAXSTEP(y, 0x142, 0xa);
        DPP_MAXSTEP(y, 0x143, 0xc);
        const float ex = dpp_movf<WAVE_SHR1>(NEGF, y);
        const float s0 = fmaxf(ex, x0);

        const float p0 = (v0 + d0) + (a0 + s0);
        const float p1 = (v1 + d1) + (a1 + y);

        const half2v hq = __builtin_bit_cast(half2v, q);
        const float q0 = (float)(MIR ? hq.y : hq.x);
        const float q1 = (float)(MIR ? hq.x : hq.y);
        const float o0 = (p0 + q0) * 0.125f;
        const float o1 = (p1 + q1) * 0.125f;

        const int row = MIR ? 127 - t : t;
        const float2 ov = MIR ? make_float2(o1, o0) : make_float2(o0, o1);
        *(float2*)(oim + (row << 7) + off) = ov;
      }
    }
  }
}

__global__ __launch_bounds__(128) void pool255_sweep(
    const float* __restrict__ x, float* __restrict__ out) {
  __shared__ unsigned part[NPIX / 2];  // fp16x2, 32 KB -> 5 blocks/CU
  const int img = blockIdx.x;
  const float* __restrict__ xim = x + (size_t)img * NPIX;
  float* __restrict__ oim = out + (size_t)img * NPIX;
  const int l = threadIdx.x & 63;

  if (threadIdx.x < 64)
    run<false>(xim, oim, part, l);
  else
    run<true>(xim, oim, part, l);
}

extern "C" void kernel_launch(void* const* d_in, const int* in_sizes, int n_in,
                              void* d_out, int out_size, void* d_ws,
                              size_t ws_size, hipStream_t stream) {
  const float* x = (const float*)d_in[0];
  float* out = (float*)d_out;
  const int n_img = in_sizes[0] / NPIX;  // 8*256 = 2048
  pool255_sweep<<<n_img, 128, 0, stream>>>(x, out);
}

// Round 8
// 63.533 us; speedup vs baseline: 1.7280x; 1.1886x over previous
//
#include <hip/hip_runtime.h>

// Pool255: out = (1/8) * sum of 8 directional cumulative-max pools.
// x: [8,256,128,128] fp32. 1024 blocks (2 waves each), 2 images per block.
//
// Wave0 sweeps rows top-down computing dirs {(-1,0),(-1,-1),(-1,+1),(0,-1)};
// wave1 sweeps bottom-up in a COLUMN-MIRRORED view (lane l <-> col 127-2l),
// which turns its 4 dirs {(1,0),(1,1),(1,-1),(0,1)} into the SAME recurrences.
// Lane l owns 2 adjacent (view-)columns {2l,2l+1}. All shift-by-1 cross-lane
// ops are DPP wave_shr:1/wave_shl:1 (pure VALU, NEGF boundary via `old`).
// Phase 0 writes fp16x2 partials to LDS; lgkm-only barrier; phase 1 combines
// with the other wave's partial and stores out (nontemporal).
//
// R8: depth-8 global prefetch (MLP to cover ~900cy HBM latency), Q[8] LDS
// prefetch, s_waitcnt lgkmcnt(0)+s_barrier instead of __syncthreads (keeps
// global prefetches in flight across the barrier), 1024-block grid-stride
// (4 blocks/CU, balanced residency, no 5-then-3 tail).

#define NPIX 16384
#define NEGF (-3.402823466e38f)

typedef __fp16 half2v __attribute__((ext_vector_type(2)));

// dst[l] = src[l -/+ 1]; invalid lanes get `oldv`.
template <int CTRL>
__device__ __forceinline__ float dpp_movf(float oldv, float src) {
  return __int_as_float(__builtin_amdgcn_update_dpp(
      __float_as_int(oldv), __float_as_int(src), CTRL, 0xf, 0xf, false));
}
#define WAVE_SHR1 0x138  // lane l reads lane l-1 (lane 0 -> old)
#define WAVE_SHL1 0x130  // lane l reads lane l+1 (lane 63 -> old)

// y = max(y, dpp_move(y)) ; masked/invalid lanes keep old=y (no-op)
#define DPP_MAXSTEP(y, ctrl, rmask)                                          \
  y = fmaxf(y, __int_as_float(__builtin_amdgcn_update_dpp(                   \
                 __float_as_int(y), __float_as_int(y), ctrl, rmask, 0xf,     \
                 false)))

// Barrier that drains only LDS (lgkm), NOT the global prefetch queue (vmcnt).
__device__ __forceinline__ void lds_barrier() {
  asm volatile("s_waitcnt lgkmcnt(0)\n\ts_barrier" ::: "memory");
}

template <bool MIR>
__device__ __forceinline__ void run(const float* __restrict__ xim,
                                    float* __restrict__ oim,
                                    unsigned* __restrict__ part, const int l) {
  const int off = MIR ? (63 - l) * 2 : l * 2;  // float index of the col pair
  const int slot = MIR ? (63 - l) : l;         // u32 slot in a part row

  float v0 = NEGF, v1 = NEGF, d0 = NEGF, d1 = NEGF, a0 = NEGF, a1 = NEGF;

  // depth-8 x-load pipeline
  float2 G[8];
#pragma unroll
  for (int k = 0; k < 8; ++k) {
    const int row = MIR ? 127 - k : k;
    G[k] = *(const float2*)(xim + (row << 7) + off);
  }

  // ---- phase 0: t = 0..63, write fp16x2 partial to LDS ----
  for (int tb = 0; tb < 64; tb += 8) {
#pragma unroll
    for (int k = 0; k < 8; ++k) {
      const int t = tb + k;
      const float2 xv = G[k];
      const int pr = t + 8;  // 8..71: tail pre-issues phase-1 x rows
      const int prow = MIR ? 127 - pr : pr;
      G[k] = *(const float2*)(xim + (prow << 7) + off);

      const float x0 = MIR ? xv.y : xv.x;
      const float x1 = MIR ? xv.x : xv.y;

      v0 = fmaxf(v0, x0);
      v1 = fmaxf(v1, x1);

      // diagonal: D[c] = max(x[c], Dprev[c-1])
      const float pd = dpp_movf<WAVE_SHR1>(NEGF, d1);
      const float nd0 = fmaxf(x0, pd);
      const float nd1 = fmaxf(x1, d0);
      d0 = nd0; d1 = nd1;

      // anti-diagonal: A[c] = max(x[c], Aprev[c+1])
      const float pa = dpp_movf<WAVE_SHL1>(NEGF, a0);
      const float na1 = fmaxf(x1, pa);
      const float na0 = fmaxf(x0, a1);
      a0 = na0; a1 = na1;

      // row inclusive prefix-max over lane totals (DPP scan)
      float y = fmaxf(x0, x1);
      DPP_MAXSTEP(y, 0x111, 0xf);  // row_shr:1
      DPP_MAXSTEP(y, 0x112, 0xf);  // row_shr:2
      DPP_MAXSTEP(y, 0x114, 0xf);  // row_shr:4
      DPP_MAXSTEP(y, 0x118, 0xf);  // row_shr:8
      DPP_MAXSTEP(y, 0x142, 0xa);  // row_bcast15 -> rows 1,3
      DPP_MAXSTEP(y, 0x143, 0xc);  // row_bcast31 -> rows 2,3
      const float ex = dpp_movf<WAVE_SHR1>(NEGF, y);
      const float s0 = fmaxf(ex, x0);

      const float p0 = (v0 + d0) + (a0 + s0);
      const float p1 = (v1 + d1) + (a1 + y);

      const int row = MIR ? 127 - t : t;
      const half2v h = MIR ? __builtin_amdgcn_cvt_pkrtz(p1, p0)
                           : __builtin_amdgcn_cvt_pkrtz(p0, p1);
      part[(row << 6) + slot] = __builtin_bit_cast(unsigned, h);
    }
  }

  lds_barrier();  // partials visible; global prefetches stay in flight

  // ---- phase 1: t = 64..127, combine + store final float2 ----
  {
    unsigned Q[8];  // depth-8 LDS partial pipeline
#pragma unroll
    for (int k = 0; k < 8; ++k) {
      const int row = MIR ? 127 - (64 + k) : (64 + k);
      Q[k] = part[(row << 6) + slot];
    }
    for (int tb = 64; tb < 128; tb += 8) {
#pragma unroll
      for (int k = 0; k < 8; ++k) {
        const int t = tb + k;
        const float2 xv = G[k];
        const int pr = (t + 8 < 128) ? t + 8 : 127;  // clamp (uniform)
        const int prow = MIR ? 127 - pr : pr;
        G[k] = *(const float2*)(xim + (prow << 7) + off);

        const unsigned q = Q[k];
        Q[k] = part[(prow << 6) + slot];  // prefetch partial row t+8

        const float x0 = MIR ? xv.y : xv.x;
        const float x1 = MIR ? xv.x : xv.y;

        v0 = fmaxf(v0, x0);
        v1 = fmaxf(v1, x1);

        const float pd = dpp_movf<WAVE_SHR1>(NEGF, d1);
        const float nd0 = fmaxf(x0, pd);
        const float nd1 = fmaxf(x1, d0);
        d0 = nd0; d1 = nd1;

        const float pa = dpp_movf<WAVE_SHL1>(NEGF, a0);
        const float na1 = fmaxf(x1, pa);
        const float na0 = fmaxf(x0, a1);
        a0 = na0; a1 = na1;

        float y = fmaxf(x0, x1);
        DPP_MAXSTEP(y, 0x111, 0xf);
        DPP_MAXSTEP(y, 0x112, 0xf);
        DPP_MAXSTEP(y, 0x114, 0xf);
        DPP_MAXSTEP(y, 0x118, 0xf);
        DPP_MAXSTEP(y, 0x142, 0xa);
        DPP_MAXSTEP(y, 0x143, 0xc);
        const float ex = dpp_movf<WAVE_SHR1>(NEGF, y);
        const float s0 = fmaxf(ex, x0);

        const float p0 = (v0 + d0) + (a0 + s0);
        const float p1 = (v1 + d1) + (a1 + y);

        const half2v hq = __builtin_bit_cast(half2v, q);
        const float q0 = (float)(MIR ? hq.y : hq.x);
        const float q1 = (float)(MIR ? hq.x : hq.y);
        const float o0 = (p0 + q0) * 0.125f;
        const float o1 = (p1 + q1) * 0.125f;

        const int row = MIR ? 127 - t : t;
        const float2 ov = MIR ? make_float2(o1, o0) : make_float2(o0, o1);
        // nontemporal: streaming output, don't evict x from L2
        __builtin_nontemporal_store(
            __builtin_bit_cast(unsigned long long, ov),
            (unsigned long long*)(oim + (row << 7) + off));
      }
    }
  }
}

__global__ __launch_bounds__(128) void pool255_sweep(
    const float* __restrict__ x, float* __restrict__ out, int n_img) {
  __shared__ unsigned part[NPIX / 2];  // fp16x2, 32 KB
  const int l = threadIdx.x & 63;
  for (int img = blockIdx.x; img < n_img; img += gridDim.x) {
    const float* __restrict__ xim = x + (size_t)img * NPIX;
    float* __restrict__ oim = out + (size_t)img * NPIX;
    if (threadIdx.x < 64)
      run<false>(xim, oim, part, l);
    else
      run<true>(xim, oim, part, l);
    lds_barrier();  // protect part[] reuse across images
  }
}

extern "C" void kernel_launch(void* const* d_in, const int* in_sizes, int n_in,
                              void* d_out, int out_size, void* d_ws,
                              size_t ws_size, hipStream_t stream) {
  const float* x = (const float*)d_in[0];
  float* out = (float*)d_out;
  const int n_img = in_sizes[0] / NPIX;  // 8*256 = 2048
  const int grid = (n_img < 1024) ? n_img : 1024;  // 2 images/block, balanced
  pool255_sweep<<<grid, 128, 0, stream>>>(x, out, n_img);
}